// Round 10
// baseline (274.482 us; speedup 1.0000x reference)
//
#include <hip/hip_runtime.h>
#include <math.h>

#define BB   16
#define NN   2048
#define FIN  6
#define FOUT 128
#define KCH  6
#define KNN  40
#define NCLS 40

// ---------------------------------------------------------------------------
// Kernel A: per-row kNN. R10: (1) dot-form distances with |x_j|^2 in
// REGISTERS (c[32], amortized over 8 rows) — NOT LDS (R8 lesson: +8KB LDS
// halved occupancy); (2) 64 unpacked hist bins (no 16-bit packing ops);
// (3) float candidate keys (keys may be negative). Selection semantics
// unchanged: exact top-40 by squared distance. Also zeroes pmax (blocks 0-15).
// LDS stays 54784 -> 2 blocks/CU; VGPR must stay <=128 (residency cliff).
// ---------------------------------------------------------------------------
__global__ __launch_bounds__(512) void knn_kernel(const float* __restrict__ x,
                                                  int* __restrict__ topi,
                                                  float* __restrict__ topv,
                                                  float* __restrict__ dinv,
                                                  float* __restrict__ pmax)
{
    __shared__ __align__(16) float xs[FIN][NN];   // 48 KB
    __shared__ unsigned int   hist[8][64];        // 2 KB (1 bin per u32)
    __shared__ float          ck[8][64];          // candidate keys (float)
    __shared__ unsigned short ci[8][64];          // candidate indices
    __shared__ unsigned int   ccnt[8];

    int bb   = blockIdx.x >> 5;                   // 32 blocks per batch
    int i0   = (blockIdx.x & 31) * 64;
    int t    = threadIdx.x;
    int lane = t & 63;
    int wv   = t >> 6;

    if (blockIdx.x < BB && t < FOUT) pmax[blockIdx.x * FOUT + t] = 0.0f;

    const float* xb = x + (size_t)bb * NN * FIN;
    for (int idx = t; idx < NN * FIN; idx += 512) {
        int j = idx / FIN, f = idx - j * FIN;
        xs[f][j] = xb[idx];
    }
    __syncthreads();                              // only block barrier

    // ---- |x_j|^2 for this lane's 32 j's, kept in registers for all 8 rows ----
    float c[32];
#pragma unroll
    for (int uu = 0; uu < 8; ++uu) {
        int j4 = uu * 64 + lane;
        float4 p0 = ((const float4*)xs[0])[j4];
        float4 p1 = ((const float4*)xs[1])[j4];
        float4 p2 = ((const float4*)xs[2])[j4];
        float4 p3 = ((const float4*)xs[3])[j4];
        float4 p4 = ((const float4*)xs[4])[j4];
        float4 p5 = ((const float4*)xs[5])[j4];
#define CNE(E, C)                                                                \
        c[uu * 4 + E] = fmaf(p5.C,p5.C, fmaf(p4.C,p4.C, fmaf(p3.C,p3.C,          \
                        fmaf(p2.C,p2.C, fmaf(p1.C,p1.C, p0.C*p0.C)))));
        CNE(0, x) CNE(1, y) CNE(2, z) CNE(3, w)
#undef CNE
    }

    for (int rr = 0; rr < 8; ++rr) {
        int i   = i0 + wv * 8 + rr;
        int row = bb * NN + i;

        float xi0 = xs[0][i], xi1 = xs[1][i], xi2 = xs[2][i],
              xi3 = xs[3][i], xi4 = xs[4][i], xi5 = xs[5][i];
        float si  = fmaf(xi5,xi5, fmaf(xi4,xi4, fmaf(xi3,xi3,
                    fmaf(xi2,xi2, fmaf(xi1,xi1, xi0*xi0)))));

        // ---- keys: d[u] = |x_j|^2 - 2<x_i,x_j>  (true dist = key + si) ----
        float d[32];
#pragma unroll
        for (int uu = 0; uu < 8; ++uu) {
            int j4 = uu * 64 + lane;              // float4 index within plane
            float4 p0 = ((const float4*)xs[0])[j4];
            float4 p1 = ((const float4*)xs[1])[j4];
            float4 p2 = ((const float4*)xs[2])[j4];
            float4 p3 = ((const float4*)xs[3])[j4];
            float4 p4 = ((const float4*)xs[4])[j4];
            float4 p5 = ((const float4*)xs[5])[j4];
#define DNE(E, C)                                                                \
            { float dt = fmaf(p5.C, xi5, fmaf(p4.C, xi4, fmaf(p3.C, xi3,         \
                         fmaf(p2.C, xi2, fmaf(p1.C, xi1, p0.C * xi0)))));        \
              d[uu * 4 + E] = fmaf(-2.0f, dt, c[uu * 4 + E]); }
            DNE(0, x) DNE(1, y) DNE(2, z) DNE(3, w)
#undef DNE
        }

        // ---- histogram select: 64 bins, dist range [0,8) -> key range ----
        float lo = -si, invw = 8.0f;
        int base = 0, pivot = 63;

        for (int pass = 0; pass < 6; ++pass) {
            hist[wv][lane] = 0u;
#pragma unroll
            for (int u = 0; u < 32; ++u) {
                float dv = d[u];
                if (dv >= lo) {
                    int bin = (int)((dv - lo) * invw);
                    if (bin < 64) atomicAdd(&hist[wv][bin], 1u);
                }
            }
            int s = (int)hist[wv][lane];
            int incl = s;
#pragma unroll
            for (int off = 1; off < 64; off <<= 1) {
                int up = __shfl_up(incl, off, 64);
                if (lane >= off) incl += up;
            }
            int total = __shfl(incl, 63, 64);

            if (base + total < KNN) {             // range too small: widen
                base += total;
                lo   += 64.0f / invw;
                invw *= 0.5f;
                continue;
            }

            unsigned long long ball = __ballot(base + incl >= KNN);
            int pl = __ffsll(ball) - 1;
            pivot    = pl;
            int cumb = base + __shfl(incl - s, pl, 64);
            int csel = base + __shfl(incl, pl, 64);

            if (csel <= 64) break;                // all candidates fit one wave

            lo   = lo + (float)pivot / invw;      // refine inside crowded bin
            invw *= 64.0f;
            base = cumb;
        }

        // ---- collect candidates (bin <= pivot; below-lo gives ib<=0) ----
        if (lane == 0) ccnt[wv] = 0u;
#pragma unroll
        for (int u = 0; u < 32; ++u) {
            int ib = (int)((d[u] - lo) * invw);   // <=0 for dv<lo
            if (ib <= pivot) {
                unsigned int slot = atomicAdd(&ccnt[wv], 1u);
                if (slot < 64u) {
                    ck[wv][slot] = d[u];
                    ci[wv][slot] = (unsigned short)((u >> 2) * 256 + (lane << 2) + (u & 3));
                }
            }
        }
        unsigned int cc = ccnt[wv];
        if (cc > 64u) cc = 64u;

        float kk = (lane < (int)cc) ? ck[wv][lane] : 3.0e38f;
        int   id = (lane < (int)cc) ? (int)ci[wv][lane] : -1;

        // ---- exact rank among <=64 candidates (float keys) ----
        int rank = 0;
        int cI = (int)cc;                         // >= KNN by pivot construction
        for (int m = 0; m < cI; ++m) {
            float km = __shfl(kk, m, 64);
            rank += (km < kk || (km == kk && m < lane)) ? 1 : 0;
        }

        float ev = 0.0f;
        if (rank < KNN) {
            ev = expf(-(kk + si));                // true dist = key + |x_i|^2
            topv[(size_t)row * KNN + rank] = ev;
            topi[(size_t)row * KNN + rank] = id;
        }
        float ssum = ev;
#pragma unroll
        for (int off = 32; off; off >>= 1) ssum += __shfl_xor(ssum, off, 64);
        if (lane == 0) dinv[row] = 1.0f / sqrtf(ssum);
    }
}

// ---------------------------------------------------------------------------
// Kernel C: sparse Chebyshev step. Block = 192 thr = 32 rows x 6 features.
// First call (topv != null) also COMPUTES wnrm = topv*dinv_i*dinv_j.
// ---------------------------------------------------------------------------
__global__ __launch_bounds__(192) void cheb_apply(const float* __restrict__ xin,
                                                  const float* __restrict__ xsub,
                                                  float* __restrict__ xout,
                                                  const int* __restrict__ topi,
                                                  const float* __restrict__ wnrm,
                                                  const float* __restrict__ topv,
                                                  const float* __restrict__ dinv,
                                                  float* __restrict__ wnrm_out,
                                                  float scale)
{
    __shared__ int   si[32 * KNN];
    __shared__ float sw[32 * KNN];
    int r0 = blockIdx.x * 32;
    int t  = threadIdx.x;
    if (topv) {
        int b = r0 >> 11;
        const float* dv = dinv + ((size_t)b << 11);
        for (int l = t; l < 32 * KNN; l += 192) {
            size_t idx = (size_t)r0 * KNN + l;
            int j = topi[idx];
            float w = topv[idx] * dinv[r0 + l / KNN] * dv[j];
            si[l] = j; sw[l] = w;
            wnrm_out[idx] = w;
        }
    } else {
        for (int l = t; l < 32 * KNN; l += 192) {
            si[l] = topi[(size_t)r0 * KNN + l];
            sw[l] = wnrm[(size_t)r0 * KNN + l];
        }
    }
    __syncthreads();

    int rl = t / FIN, f = t - rl * FIN;
    int r  = r0 + rl;
    int b  = r >> 11;
    const float* xbase = xin + (size_t)b * NN * FIN + f;
    const int*   sip = si + rl * KNN;
    const float* swp = sw + rl * KNN;
    float a = xin[(size_t)r * FIN + f];
#pragma unroll 8
    for (int s = 0; s < KNN; ++s)
        a = fmaf(-swp[s], xbase[(size_t)sip[s] * FIN], a);
    a *= scale;
    if (xsub) a -= xsub[(size_t)r * FIN + f];
    xout[(size_t)r * FIN + f] = a;
}

// ---------------------------------------------------------------------------
// Kernel D: out = relu( sum_k x_k @ W1[k] + b1 ). Block = 512 thr = 16 rows;
// W1 staged once per block; per-feature block max -> atomicMax into pmax
// (uint-punned; valid since out >= 0 and pmax zeroed by knn).
// ---------------------------------------------------------------------------
__global__ __launch_bounds__(512) void chebout_kernel(const float* __restrict__ x,
                                                      const float* __restrict__ xks,
                                                      const float* __restrict__ W1,
                                                      const float* __restrict__ b1,
                                                      float* __restrict__ outb,
                                                      float* __restrict__ pmax)
{
    __shared__ float W1s[KCH * FIN * FOUT];
    __shared__ float b1s[FOUT];
    __shared__ float xk[16][KCH * FIN];
    __shared__ float mx[4][FOUT];
    int r0 = blockIdx.x * 16;
    int t  = threadIdx.x;
    for (int l = t; l < KCH * FIN * FOUT; l += 512) W1s[l] = W1[l];
    if (t < FOUT) b1s[t] = b1[t];
    for (int l = t; l < 16 * KCH * FIN; l += 512) {
        int rl = l / (KCH * FIN), kf = l % (KCH * FIN);
        int k = kf / FIN, f = kf % FIN;
        int r = r0 + rl;
        xk[rl][kf] = (k == 0) ? x[(size_t)r * FIN + f]
                              : xks[(size_t)(k - 1) * BB * NN * FIN + (size_t)r * FIN + f];
    }
    __syncthreads();
    int fo = t & 127;
    float om = 0.0f;
#pragma unroll
    for (int it = 0; it < 4; ++it) {
        int rl = (t >> 7) + it * 4;
        float acc = b1s[fo];
#pragma unroll
        for (int kf = 0; kf < KCH * FIN; ++kf)
            acc = fmaf(xk[rl][kf], W1s[kf * FOUT + fo], acc);
        float o = fmaxf(acc, 0.0f);
        outb[(size_t)(r0 + rl) * FOUT + fo] = o;
        om = fmaxf(om, o);
    }
    mx[t >> 7][fo] = om;
    __syncthreads();
    if (t < FOUT) {
        float m = fmaxf(fmaxf(mx[0][t], mx[1][t]), fmaxf(mx[2][t], mx[3][t]));
        int b = r0 >> 11;
        atomicMax((unsigned int*)&pmax[(size_t)b * FOUT + t], __float_as_uint(m));
    }
}

// ---------------------------------------------------------------------------
// Kernel F: FUSED lout + M-partial GEMM (proven R7 version).
// ---------------------------------------------------------------------------
__global__ __launch_bounds__(1024) void loutmsq_kernel(const float* __restrict__ outb,
                                                       const int* __restrict__ topi,
                                                       const float* __restrict__ wnrm,
                                                       float* __restrict__ mchunk)
{
    int id  = blockIdx.x;                  // 256
    int xcd = id & 7, k = id >> 3;
    int bb  = xcd + 8 * (k >> 4);
    int nch = k & 15;                      // chunk of 128 rows
    int t   = threadIdx.x;

    __shared__ __align__(16) float aT[64][FOUT];   // 32 KB
    __shared__ __align__(16) float bT[64][FOUT];   // 32 KB

    const float* ob = outb + (size_t)bb * NN * FOUT;
    float acc[4][4] = {{0.f}};
    int tx = t & 31, ty = t >> 5;          // GEMM: f-block, g-block
    int grl = t >> 4;                      // gather: row 0..63
    int gfq = (t & 15) * 2;                // gather: float4 pair base

    for (int st = 0; st < 2; ++st) {
        int n0 = nch * 128 + st * 64;
        {
            const float4* src = (const float4*)(ob + (size_t)n0 * FOUT);
            float4* dst = (float4*)aT;
            dst[t]        = src[t];
            dst[t + 1024] = src[t + 1024];
        }
        __syncthreads();
        {
            int r = n0 + grl;
            const int*   ti = topi + ((size_t)bb * NN + r) * KNN;
            const float* tw = wnrm + ((size_t)bb * NN + r) * KNN;
            float4 a0 = ((const float4*)aT[grl])[gfq];
            float4 a1 = ((const float4*)aT[grl])[gfq + 1];
#pragma unroll 8
            for (int s = 0; s < KNN; ++s) {
                int j = ti[s]; float w = tw[s];
                const float4* jr = (const float4*)(ob + (size_t)j * FOUT);
                float4 v0 = jr[gfq], v1 = jr[gfq + 1];
                a0.x = fmaf(-w, v0.x, a0.x); a0.y = fmaf(-w, v0.y, a0.y);
                a0.z = fmaf(-w, v0.z, a0.z); a0.w = fmaf(-w, v0.w, a0.w);
                a1.x = fmaf(-w, v1.x, a1.x); a1.y = fmaf(-w, v1.y, a1.y);
                a1.z = fmaf(-w, v1.z, a1.z); a1.w = fmaf(-w, v1.w, a1.w);
            }
            ((float4*)bT[grl])[gfq]     = a0;
            ((float4*)bT[grl])[gfq + 1] = a1;
        }
        __syncthreads();
#pragma unroll 8
        for (int qq = 0; qq < 64; ++qq) {
            float4 av = ((const float4*)aT[qq])[tx];
            float4 bv = ((const float4*)bT[qq])[ty];
            float af[4] = {av.x, av.y, av.z, av.w};
            float bg[4] = {bv.x, bv.y, bv.z, bv.w};
#pragma unroll
            for (int ii = 0; ii < 4; ++ii)
#pragma unroll
                for (int jj = 0; jj < 4; ++jj)
                    acc[ii][jj] = fmaf(af[ii], bg[jj], acc[ii][jj]);
        }
        __syncthreads();
    }
    size_t basem = ((size_t)bb * 16 + nch) << 14;    // 16384 entries per tile
#pragma unroll
    for (int ii = 0; ii < 4; ++ii) {
        float4 v = make_float4(acc[ii][0], acc[ii][1], acc[ii][2], acc[ii][3]);
        *(float4*)&mchunk[basem + (size_t)(tx * 4 + ii) * FOUT + ty * 4] = v;
    }
}

// ---------------------------------------------------------------------------
// Kernel F2: sum the 16 n-chunk partials per M entry, square, block-reduce.
// ---------------------------------------------------------------------------
__global__ __launch_bounds__(256) void mred_kernel(const float* __restrict__ mchunk,
                                                   float* __restrict__ mpart)
{
    int t = threadIdx.x;
    size_t E = ((size_t)blockIdx.x * 256 + t) * 4;   // 4 entries per thread
    int bb = (int)(E >> 14);
    int fg = (int)(E & 16383);
    float4 a = make_float4(0.f, 0.f, 0.f, 0.f);
    for (int c = 0; c < 16; ++c) {
        float4 v = *(const float4*)&mchunk[((size_t)(bb * 16 + c) << 14) + fg];
        a.x += v.x; a.y += v.y; a.z += v.z; a.w += v.w;
    }
    float s = a.x * a.x + a.y * a.y + a.z * a.z + a.w * a.w;
#pragma unroll
    for (int off = 32; off; off >>= 1) s += __shfl_down(s, off, 64);
    __shared__ float ws[4];
    if ((t & 63) == 0) ws[t >> 6] = s;
    __syncthreads();
    if (t == 0) mpart[blockIdx.x] = ws[0] + ws[1] + ws[2] + ws[3];
}

// ---------------------------------------------------------------------------
// Kernel H: FC -> logits (blocks 0..15) + reg reduction (block 16).
// ---------------------------------------------------------------------------
__global__ __launch_bounds__(128) void logits_kernel(const float* __restrict__ pmax,
                                                     const float* __restrict__ fcw,
                                                     const float* __restrict__ fcb,
                                                     const float* __restrict__ mpart,
                                                     float* __restrict__ dout)
{
    int b = blockIdx.x, t = threadIdx.x;
    if (b == BB) {                         // final reg reduction (256 partials)
        float s = mpart[t] + mpart[t + 128];
#pragma unroll
        for (int off = 32; off; off >>= 1) s += __shfl_down(s, off, 64);
        __shared__ float ws[2];
        if ((t & 63) == 0) ws[t >> 6] = s;
        __syncthreads();
        if (t == 0) dout[BB * NCLS] = ws[0] + ws[1];
        return;
    }
    __shared__ float pooled[FOUT];
    pooled[t] = pmax[(size_t)b * FOUT + t];
    __syncthreads();
    if (t < NCLS) {
        float acc = fcb[t];
        for (int f = 0; f < FOUT; ++f) acc = fmaf(pooled[f], fcw[f * NCLS + t], acc);
        dout[b * NCLS + t] = acc;
    }
}

// ---------------------------------------------------------------------------
extern "C" void kernel_launch(void* const* d_in, const int* in_sizes, int n_in,
                              void* d_out, int out_size, void* d_ws, size_t ws_size,
                              hipStream_t stream)
{
    const float* x   = (const float*)d_in[0];
    const float* W1  = (const float*)d_in[5];
    const float* b1  = (const float*)d_in[6];
    const float* fcw = (const float*)d_in[7];
    const float* fcb = (const float*)d_in[8];

    char* p = (char*)d_ws;
    auto alloc = [&](size_t bytes) { void* q = (void*)p; p += (bytes + 255) & ~(size_t)255; return q; };
    int*   topi   = (int*)  alloc((size_t)BB * NN * KNN * 4);
    float* topv   = (float*)alloc((size_t)BB * NN * KNN * 4);
    float* dinv   = (float*)alloc((size_t)BB * NN * 4);
    float* wnrm   = (float*)alloc((size_t)BB * NN * KNN * 4);
    float* xks    = (float*)alloc((size_t)5 * BB * NN * FIN * 4);    // x1..x5
    float* outb   = (float*)alloc((size_t)BB * NN * FOUT * 4);
    float* mchunk = (float*)alloc((size_t)BB * 16 * FOUT * FOUT * 4); // 16.8 MB
    float* mpart  = (float*)alloc(256 * 4);
    float* pmax   = (float*)alloc((size_t)BB * FOUT * 4);

    const size_t ST = (size_t)BB * NN * FIN;   // per-Chebyshev-order stride

    knn_kernel<<<512, 512, 0, stream>>>(x, topi, topv, dinv, pmax);

    // cheb1 also computes + writes wnrm (replaces weight_kernel)
    cheb_apply<<<1024, 192, 0, stream>>>(x,            nullptr,      xks + 0 * ST, topi, nullptr, topv, dinv, wnrm, 1.0f);
    cheb_apply<<<1024, 192, 0, stream>>>(xks + 0 * ST, x,            xks + 1 * ST, topi, wnrm, nullptr, nullptr, nullptr, 2.0f);
    cheb_apply<<<1024, 192, 0, stream>>>(xks + 1 * ST, xks + 0 * ST, xks + 2 * ST, topi, wnrm, nullptr, nullptr, nullptr, 2.0f);
    cheb_apply<<<1024, 192, 0, stream>>>(xks + 2 * ST, xks + 1 * ST, xks + 3 * ST, topi, wnrm, nullptr, nullptr, nullptr, 2.0f);
    cheb_apply<<<1024, 192, 0, stream>>>(xks + 3 * ST, xks + 2 * ST, xks + 4 * ST, topi, wnrm, nullptr, nullptr, nullptr, 2.0f);

    chebout_kernel<<<BB * NN / 16, 512, 0, stream>>>(x, xks, W1, b1, outb, pmax);
    loutmsq_kernel<<<256, 1024, 0, stream>>>(outb, topi, wnrm, mchunk);
    mred_kernel<<<256, 256, 0, stream>>>(mchunk, mpart);
    logits_kernel<<<BB + 1, 128, 0, stream>>>(pmax, fcw, fcb, mpart, (float*)d_out);
}

// Round 11
// 226.593 us; speedup vs baseline: 1.2113x; 1.2113x over previous
//
#include <hip/hip_runtime.h>
#include <math.h>

#define BB   16
#define NN   2048
#define FIN  6
#define FOUT 128
#define KCH  6
#define KNN  40
#define NCLS 40

// ---------------------------------------------------------------------------
// Kernel A: per-row kNN — EXACT R6/R9 version. FROZEN.
// Proven: 99.0 us, VGPR 52, LDS 54784, 2 blocks/CU, VALUBusy ~70%.
// HARD CONSTRAINT (verified R8 + R10): VGPR must stay <= 64. Crossing 64
// halves residency (occupancy 38% -> 22%) and costs +50% runtime regardless
// of instruction savings. d[32] + addressing = 52 VGPR is register-optimal.
// ---------------------------------------------------------------------------
__global__ __launch_bounds__(512) void knn_kernel(const float* __restrict__ x,
                                                  int* __restrict__ topi,
                                                  float* __restrict__ topv,
                                                  float* __restrict__ dinv)
{
    __shared__ __align__(16) float xs[FIN][NN];   // 48 KB
    __shared__ unsigned int   hist[8][64];        // 2 KB (2 bins per u32)
    __shared__ unsigned int   ck[8][64];          // candidate keys
    __shared__ unsigned short ci[8][64];          // candidate indices
    __shared__ unsigned int   ccnt[8];

    int bb   = blockIdx.x >> 5;                   // 32 blocks per batch
    int i0   = (blockIdx.x & 31) * 64;
    int t    = threadIdx.x;
    int lane = t & 63;
    int wv   = t >> 6;

    const float* xb = x + (size_t)bb * NN * FIN;
    for (int idx = t; idx < NN * FIN; idx += 512) {
        int j = idx / FIN, f = idx - j * FIN;
        xs[f][j] = xb[idx];
    }
    __syncthreads();                              // only block barrier

    for (int rr = 0; rr < 8; ++rr) {
        int i   = i0 + wv * 8 + rr;
        int row = bb * NN + i;

        float xi0 = xs[0][i], xi1 = xs[1][i], xi2 = xs[2][i],
              xi3 = xs[3][i], xi4 = xs[4][i], xi5 = xs[5][i];

        float d[32];
#pragma unroll
        for (int uu = 0; uu < 8; ++uu) {
            int j4 = uu * 64 + lane;              // float4 index within plane
            float4 p0 = ((const float4*)xs[0])[j4];
            float4 p1 = ((const float4*)xs[1])[j4];
            float4 p2 = ((const float4*)xs[2])[j4];
            float4 p3 = ((const float4*)xs[3])[j4];
            float4 p4 = ((const float4*)xs[4])[j4];
            float4 p5 = ((const float4*)xs[5])[j4];
#define DNE(E, C)                                                                \
            { float q0 = p0.C - xi0, q1 = p1.C - xi1, q2 = p2.C - xi2,           \
                    q3 = p3.C - xi3, q4 = p4.C - xi4, q5 = p5.C - xi5;           \
              d[uu * 4 + E] = fmaf(q5,q5, fmaf(q4,q4, fmaf(q3,q3,                \
                              fmaf(q2,q2, fmaf(q1,q1, q0*q0)))));  }
            DNE(0, x) DNE(1, y) DNE(2, z) DNE(3, w)
#undef DNE
        }

        float lo = 0.0f, invw = 16.0f;            // 128 bins over [0,8)
        int base = 0, pivot = 127;

        for (int pass = 0; pass < 6; ++pass) {
            hist[wv][lane] = 0u;
#pragma unroll
            for (int u = 0; u < 32; ++u) {
                float dv = d[u];
                if (dv >= lo) {
                    int bin = (int)((dv - lo) * invw);
                    if (bin < 128)
                        atomicAdd(&hist[wv][bin >> 1], 1u << ((bin & 1) << 4));
                }
            }
            unsigned int h = hist[wv][lane];
            int b0 = (int)(h & 0xFFFFu), b1 = (int)(h >> 16);
            int s = b0 + b1;
            int incl = s;
#pragma unroll
            for (int off = 1; off < 64; off <<= 1) {
                int up = __shfl_up(incl, off, 64);
                if (lane >= off) incl += up;
            }
            int total = __shfl(incl, 63, 64);

            if (base + total < KNN) {             // range too small: widen
                base += total;
                lo   += 128.0f / invw;
                invw *= 0.5f;
                continue;
            }

            unsigned long long ball = __ballot(base + incl >= KNN);
            int pl = __ffsll(ball) - 1;
            int p_ = 0, cb_ = 0, cs_ = 0;
            if (lane == pl) {
                int cbefore = base + incl - s;
                if (cbefore + b0 >= KNN) { p_ = pl * 2;     cb_ = cbefore;      cs_ = cbefore + b0; }
                else                     { p_ = pl * 2 + 1; cb_ = cbefore + b0; cs_ = cbefore + b0 + b1; }
            }
            pivot    = __shfl(p_, pl, 64);
            int cumb = __shfl(cb_, pl, 64);
            int csel = __shfl(cs_, pl, 64);

            if (csel <= 64) break;                // all candidates fit one wave

            lo   = lo + (float)pivot / invw;      // refine inside crowded bin
            invw *= 128.0f;
            base = cumb;
        }

        if (lane == 0) ccnt[wv] = 0u;
#pragma unroll
        for (int u = 0; u < 32; ++u) {
            int ib = (int)((d[u] - lo) * invw);   // negative for dv<lo
            if (ib <= pivot) {
                unsigned int slot = atomicAdd(&ccnt[wv], 1u);
                if (slot < 64u) {
                    ck[wv][slot] = __float_as_uint(d[u]);
                    ci[wv][slot] = (unsigned short)((u >> 2) * 256 + (lane << 2) + (u & 3));
                }
            }
        }
        unsigned int c = ccnt[wv];
        if (c > 64u) c = 64u;

        unsigned int kk = (lane < (int)c) ? ck[wv][lane] : 0xFFFFFFFFu;
        int          id = (lane < (int)c) ? (int)ci[wv][lane] : -1;

        int rank = 0;
        int cI = (int)c;                          // >= KNN by pivot construction
        for (int m = 0; m < cI; ++m) {
            unsigned int km = __shfl(kk, m, 64);
            rank += (km < kk || (km == kk && m < lane)) ? 1 : 0;
        }

        float ev = 0.0f;
        if (rank < KNN) {
            ev = expf(-__uint_as_float(kk));
            topv[(size_t)row * KNN + rank] = ev;
            topi[(size_t)row * KNN + rank] = id;
        }
        float ssum = ev;
#pragma unroll
        for (int off = 32; off; off >>= 1) ssum += __shfl_xor(ssum, off, 64);
        if (lane == 0) dinv[row] = 1.0f / sqrtf(ssum);
    }
}

// ---------------------------------------------------------------------------
// Kernel C: sparse Chebyshev step. Block = 192 thr = 32 rows x 6 features.
// First call (topv != null) also COMPUTES wnrm = topv*dinv_i*dinv_j.
// ---------------------------------------------------------------------------
__global__ __launch_bounds__(192) void cheb_apply(const float* __restrict__ xin,
                                                  const float* __restrict__ xsub,
                                                  float* __restrict__ xout,
                                                  const int* __restrict__ topi,
                                                  const float* __restrict__ wnrm,
                                                  const float* __restrict__ topv,
                                                  const float* __restrict__ dinv,
                                                  float* __restrict__ wnrm_out,
                                                  float scale)
{
    __shared__ int   si[32 * KNN];
    __shared__ float sw[32 * KNN];
    int r0 = blockIdx.x * 32;
    int t  = threadIdx.x;
    if (topv) {
        int b = r0 >> 11;
        const float* dv = dinv + ((size_t)b << 11);
        for (int l = t; l < 32 * KNN; l += 192) {
            size_t idx = (size_t)r0 * KNN + l;
            int j = topi[idx];
            float w = topv[idx] * dinv[r0 + l / KNN] * dv[j];
            si[l] = j; sw[l] = w;
            wnrm_out[idx] = w;
        }
    } else {
        for (int l = t; l < 32 * KNN; l += 192) {
            si[l] = topi[(size_t)r0 * KNN + l];
            sw[l] = wnrm[(size_t)r0 * KNN + l];
        }
    }
    __syncthreads();

    int rl = t / FIN, f = t - rl * FIN;
    int r  = r0 + rl;
    int b  = r >> 11;
    const float* xbase = xin + (size_t)b * NN * FIN + f;
    const int*   sip = si + rl * KNN;
    const float* swp = sw + rl * KNN;
    float a = xin[(size_t)r * FIN + f];
#pragma unroll 8
    for (int s = 0; s < KNN; ++s)
        a = fmaf(-swp[s], xbase[(size_t)sip[s] * FIN], a);
    a *= scale;
    if (xsub) a -= xsub[(size_t)r * FIN + f];
    xout[(size_t)r * FIN + f] = a;
}

// ---------------------------------------------------------------------------
// Kernel D: out = relu( sum_k x_k @ W1[k] + b1 ). Block = 512 thr = 16 rows;
// W1 staged once per block; per-feature block max -> atomicMax into pmax
// (uint-punned; valid since out >= 0 and pmax zeroed by memsetAsync).
// ---------------------------------------------------------------------------
__global__ __launch_bounds__(512) void chebout_kernel(const float* __restrict__ x,
                                                      const float* __restrict__ xks,
                                                      const float* __restrict__ W1,
                                                      const float* __restrict__ b1,
                                                      float* __restrict__ outb,
                                                      float* __restrict__ pmax)
{
    __shared__ float W1s[KCH * FIN * FOUT];
    __shared__ float b1s[FOUT];
    __shared__ float xk[16][KCH * FIN];
    __shared__ float mx[4][FOUT];
    int r0 = blockIdx.x * 16;
    int t  = threadIdx.x;
    for (int l = t; l < KCH * FIN * FOUT; l += 512) W1s[l] = W1[l];
    if (t < FOUT) b1s[t] = b1[t];
    for (int l = t; l < 16 * KCH * FIN; l += 512) {
        int rl = l / (KCH * FIN), kf = l % (KCH * FIN);
        int k = kf / FIN, f = kf % FIN;
        int r = r0 + rl;
        xk[rl][kf] = (k == 0) ? x[(size_t)r * FIN + f]
                              : xks[(size_t)(k - 1) * BB * NN * FIN + (size_t)r * FIN + f];
    }
    __syncthreads();
    int fo = t & 127;
    float om = 0.0f;
#pragma unroll
    for (int it = 0; it < 4; ++it) {
        int rl = (t >> 7) + it * 4;
        float acc = b1s[fo];
#pragma unroll
        for (int kf = 0; kf < KCH * FIN; ++kf)
            acc = fmaf(xk[rl][kf], W1s[kf * FOUT + fo], acc);
        float o = fmaxf(acc, 0.0f);
        outb[(size_t)(r0 + rl) * FOUT + fo] = o;
        om = fmaxf(om, o);
    }
    mx[t >> 7][fo] = om;
    __syncthreads();
    if (t < FOUT) {
        float m = fmaxf(fmaxf(mx[0][t], mx[1][t]), fmaxf(mx[2][t], mx[3][t]));
        int b = r0 >> 11;
        atomicMax((unsigned int*)&pmax[(size_t)b * FOUT + t], __float_as_uint(m));
    }
}

// ---------------------------------------------------------------------------
// Kernel F: FUSED lout + M-partial GEMM (proven R7 version).
// ---------------------------------------------------------------------------
__global__ __launch_bounds__(1024) void loutmsq_kernel(const float* __restrict__ outb,
                                                       const int* __restrict__ topi,
                                                       const float* __restrict__ wnrm,
                                                       float* __restrict__ mchunk)
{
    int id  = blockIdx.x;                  // 256
    int xcd = id & 7, k = id >> 3;
    int bb  = xcd + 8 * (k >> 4);
    int nch = k & 15;                      // chunk of 128 rows
    int t   = threadIdx.x;

    __shared__ __align__(16) float aT[64][FOUT];   // 32 KB
    __shared__ __align__(16) float bT[64][FOUT];   // 32 KB

    const float* ob = outb + (size_t)bb * NN * FOUT;
    float acc[4][4] = {{0.f}};
    int tx = t & 31, ty = t >> 5;          // GEMM: f-block, g-block
    int grl = t >> 4;                      // gather: row 0..63
    int gfq = (t & 15) * 2;                // gather: float4 pair base

    for (int st = 0; st < 2; ++st) {
        int n0 = nch * 128 + st * 64;
        {
            const float4* src = (const float4*)(ob + (size_t)n0 * FOUT);
            float4* dst = (float4*)aT;
            dst[t]        = src[t];
            dst[t + 1024] = src[t + 1024];
        }
        __syncthreads();
        {
            int r = n0 + grl;
            const int*   ti = topi + ((size_t)bb * NN + r) * KNN;
            const float* tw = wnrm + ((size_t)bb * NN + r) * KNN;
            float4 a0 = ((const float4*)aT[grl])[gfq];
            float4 a1 = ((const float4*)aT[grl])[gfq + 1];
#pragma unroll 8
            for (int s = 0; s < KNN; ++s) {
                int j = ti[s]; float w = tw[s];
                const float4* jr = (const float4*)(ob + (size_t)j * FOUT);
                float4 v0 = jr[gfq], v1 = jr[gfq + 1];
                a0.x = fmaf(-w, v0.x, a0.x); a0.y = fmaf(-w, v0.y, a0.y);
                a0.z = fmaf(-w, v0.z, a0.z); a0.w = fmaf(-w, v0.w, a0.w);
                a1.x = fmaf(-w, v1.x, a1.x); a1.y = fmaf(-w, v1.y, a1.y);
                a1.z = fmaf(-w, v1.z, a1.z); a1.w = fmaf(-w, v1.w, a1.w);
            }
            ((float4*)bT[grl])[gfq]     = a0;
            ((float4*)bT[grl])[gfq + 1] = a1;
        }
        __syncthreads();
#pragma unroll 8
        for (int qq = 0; qq < 64; ++qq) {
            float4 av = ((const float4*)aT[qq])[tx];
            float4 bv = ((const float4*)bT[qq])[ty];
            float af[4] = {av.x, av.y, av.z, av.w};
            float bg[4] = {bv.x, bv.y, bv.z, bv.w};
#pragma unroll
            for (int ii = 0; ii < 4; ++ii)
#pragma unroll
                for (int jj = 0; jj < 4; ++jj)
                    acc[ii][jj] = fmaf(af[ii], bg[jj], acc[ii][jj]);
        }
        __syncthreads();
    }
    size_t basem = ((size_t)bb * 16 + nch) << 14;    // 16384 entries per tile
#pragma unroll
    for (int ii = 0; ii < 4; ++ii) {
        float4 v = make_float4(acc[ii][0], acc[ii][1], acc[ii][2], acc[ii][3]);
        *(float4*)&mchunk[basem + (size_t)(tx * 4 + ii) * FOUT + ty * 4] = v;
    }
}

// ---------------------------------------------------------------------------
// Kernel F2: sum the 16 n-chunk partials per M entry, square, block-reduce.
// ---------------------------------------------------------------------------
__global__ __launch_bounds__(256) void mred_kernel(const float* __restrict__ mchunk,
                                                   float* __restrict__ mpart)
{
    int t = threadIdx.x;
    size_t E = ((size_t)blockIdx.x * 256 + t) * 4;   // 4 entries per thread
    int bb = (int)(E >> 14);
    int fg = (int)(E & 16383);
    float4 a = make_float4(0.f, 0.f, 0.f, 0.f);
    for (int c = 0; c < 16; ++c) {
        float4 v = *(const float4*)&mchunk[((size_t)(bb * 16 + c) << 14) + fg];
        a.x += v.x; a.y += v.y; a.z += v.z; a.w += v.w;
    }
    float s = a.x * a.x + a.y * a.y + a.z * a.z + a.w * a.w;
#pragma unroll
    for (int off = 32; off; off >>= 1) s += __shfl_down(s, off, 64);
    __shared__ float ws[4];
    if ((t & 63) == 0) ws[t >> 6] = s;
    __syncthreads();
    if (t == 0) mpart[blockIdx.x] = ws[0] + ws[1] + ws[2] + ws[3];
}

// ---------------------------------------------------------------------------
// Kernel H: FC -> logits (blocks 0..15) + reg reduction (block 16).
// ---------------------------------------------------------------------------
__global__ __launch_bounds__(128) void logits_kernel(const float* __restrict__ pmax,
                                                     const float* __restrict__ fcw,
                                                     const float* __restrict__ fcb,
                                                     const float* __restrict__ mpart,
                                                     float* __restrict__ dout)
{
    int b = blockIdx.x, t = threadIdx.x;
    if (b == BB) {                         // final reg reduction (256 partials)
        float s = mpart[t] + mpart[t + 128];
#pragma unroll
        for (int off = 32; off; off >>= 1) s += __shfl_down(s, off, 64);
        __shared__ float ws[2];
        if ((t & 63) == 0) ws[t >> 6] = s;
        __syncthreads();
        if (t == 0) dout[BB * NCLS] = ws[0] + ws[1];
        return;
    }
    __shared__ float pooled[FOUT];
    pooled[t] = pmax[(size_t)b * FOUT + t];
    __syncthreads();
    if (t < NCLS) {
        float acc = fcb[t];
        for (int f = 0; f < FOUT; ++f) acc = fmaf(pooled[f], fcw[f * NCLS + t], acc);
        dout[b * NCLS + t] = acc;
    }
}

// ---------------------------------------------------------------------------
extern "C" void kernel_launch(void* const* d_in, const int* in_sizes, int n_in,
                              void* d_out, int out_size, void* d_ws, size_t ws_size,
                              hipStream_t stream)
{
    const float* x   = (const float*)d_in[0];
    const float* W1  = (const float*)d_in[5];
    const float* b1  = (const float*)d_in[6];
    const float* fcw = (const float*)d_in[7];
    const float* fcb = (const float*)d_in[8];

    char* p = (char*)d_ws;
    auto alloc = [&](size_t bytes) { void* q = (void*)p; p += (bytes + 255) & ~(size_t)255; return q; };
    int*   topi   = (int*)  alloc((size_t)BB * NN * KNN * 4);
    float* topv   = (float*)alloc((size_t)BB * NN * KNN * 4);
    float* dinv   = (float*)alloc((size_t)BB * NN * 4);
    float* wnrm   = (float*)alloc((size_t)BB * NN * KNN * 4);
    float* xks    = (float*)alloc((size_t)5 * BB * NN * FIN * 4);    // x1..x5
    float* outb   = (float*)alloc((size_t)BB * NN * FOUT * 4);
    float* mchunk = (float*)alloc((size_t)BB * 16 * FOUT * FOUT * 4); // 16.8 MB
    float* mpart  = (float*)alloc(256 * 4);
    float* pmax   = (float*)alloc((size_t)BB * FOUT * 4);

    const size_t ST = (size_t)BB * NN * FIN;   // per-Chebyshev-order stride

    hipMemsetAsync(pmax, 0, (size_t)BB * FOUT * 4, stream);  // atomicMax target

    knn_kernel<<<512, 512, 0, stream>>>(x, topi, topv, dinv);

    // cheb1 also computes + writes wnrm (replaces weight_kernel)
    cheb_apply<<<1024, 192, 0, stream>>>(x,            nullptr,      xks + 0 * ST, topi, nullptr, topv, dinv, wnrm, 1.0f);
    cheb_apply<<<1024, 192, 0, stream>>>(xks + 0 * ST, x,            xks + 1 * ST, topi, wnrm, nullptr, nullptr, nullptr, 2.0f);
    cheb_apply<<<1024, 192, 0, stream>>>(xks + 1 * ST, xks + 0 * ST, xks + 2 * ST, topi, wnrm, nullptr, nullptr, nullptr, 2.0f);
    cheb_apply<<<1024, 192, 0, stream>>>(xks + 2 * ST, xks + 1 * ST, xks + 3 * ST, topi, wnrm, nullptr, nullptr, nullptr, 2.0f);
    cheb_apply<<<1024, 192, 0, stream>>>(xks + 3 * ST, xks + 2 * ST, xks + 4 * ST, topi, wnrm, nullptr, nullptr, nullptr, 2.0f);

    chebout_kernel<<<BB * NN / 16, 512, 0, stream>>>(x, xks, W1, b1, outb, pmax);
    loutmsq_kernel<<<256, 1024, 0, stream>>>(outb, topi, wnrm, mchunk);
    mred_kernel<<<256, 256, 0, stream>>>(mchunk, mpart);
    logits_kernel<<<BB + 1, 128, 0, stream>>>(pmax, fcw, fcb, mpart, (float*)d_out);
}